// Round 1
// baseline (119397.705 us; speedup 1.0000x reference)
//
#include <hip/hip_runtime.h>
#include <hip/hip_cooperative_groups.h>

namespace cg = cooperative_groups;

#define H 4096
#define IN 64
#define OUTD 64
#define SEQ 4096
#define NBLK 256
#define ROWS_PER_BLK 16
#define NTHR 1024

__device__ __forceinline__ float row16_allreduce(float x) {
    // all-reduce across each 16-lane DPP row via rotate-and-add (VALU pipe)
    x += __int_as_float(__builtin_amdgcn_update_dpp(0, __float_as_int(x), 0x128, 0xf, 0xf, false)); // row_ror:8
    x += __int_as_float(__builtin_amdgcn_update_dpp(0, __float_as_int(x), 0x124, 0xf, 0xf, false)); // row_ror:4
    x += __int_as_float(__builtin_amdgcn_update_dpp(0, __float_as_int(x), 0x122, 0xf, 0xf, false)); // row_ror:2
    x += __int_as_float(__builtin_amdgcn_update_dpp(0, __float_as_int(x), 0x121, 0xf, 0xf, false)); // row_ror:1
    return x;
}

__global__ __launch_bounds__(NTHR, 4)
void esn_scan(const float* __restrict__ inputs,   // (SEQ, IN)
              const float* __restrict__ W_in,     // (H, IN)
              const float* __restrict__ W_res,    // (H, H)
              float* __restrict__ out_states,     // (SEQ, H) region of d_out
              const float* __restrict__ zero_state) // H floats, zeroed
{
    __shared__ alignas(16) float s_state[H];            // swizzled quads
    __shared__ alignas(16) float s_win[ROWS_PER_BLK][IN];
    __shared__ alignas(16) float s_part[16][16];        // [wave][row]
    __shared__ alignas(16) float s_u[IN];

    const int tid  = threadIdx.x;
    const int row0 = blockIdx.x * ROWS_PER_BLK;
    const int wave = tid >> 6;
    const int lane = tid & 63;
    const int rg   = lane >> 4;   // 0..3  (row group: rows 4*rg .. 4*rg+3)
    const int cgi  = lane & 15;   // 0..15 (col group: cols wave*256 + cgi*16 .. +16)

    // ---- stage W_in rows for this block (once)
    for (int idx = tid; idx < ROWS_PER_BLK * IN; idx += NTHR)
        (&s_win[0][0])[idx] = W_in[(size_t)row0 * IN + idx];

    // ---- load this lane's 64 fp32 weights into registers (once)
    float w[4][16];
    const int col0 = wave * 256 + cgi * 16;
#pragma unroll
    for (int j = 0; j < 4; ++j) {
        const float* src = W_res + (size_t)(row0 + 4 * rg + j) * H + col0;
#pragma unroll
        for (int q = 0; q < 4; ++q) {
            float4 v = *(const float4*)(src + 4 * q);
            w[j][4 * q + 0] = v.x; w[j][4 * q + 1] = v.y;
            w[j][4 * q + 2] = v.z; w[j][4 * q + 3] = v.w;
        }
    }

    cg::grid_group grid = cg::this_grid();
    float4* s_state4 = (float4*)s_state;

    for (int t = 0; t < SEQ; ++t) {
        // ---- phase 1: stage previous state (global -> LDS, swizzled quads) + u_t
        {
            const float4* gsrc = (const float4*)(t == 0 ? zero_state
                                                        : out_states + (size_t)(t - 1) * H);
            float4 v = gsrc[tid];                 // quad qi = tid
            const int w_  = tid >> 6;
            const int wi  = tid & 63;
            const int cg_ = wi >> 2;
            const int q_  = wi & 3;
            s_state4[w_ * 64 + q_ * 16 + cg_] = v; // slot = w*64 + q*16 + cg
            if (tid < 16)
                ((float4*)s_u)[tid] = ((const float4*)(inputs + (size_t)t * IN))[tid];
        }
        __syncthreads();

        // ---- phase 2: 4 rows x 16 cols of FMA per lane, weights in VGPRs
        float a0 = 0.f, a1 = 0.f, a2 = 0.f, a3 = 0.f;
#pragma unroll
        for (int q = 0; q < 4; ++q) {
            float4 sv = s_state4[wave * 64 + q * 16 + cgi];
            a0 = fmaf(w[0][4*q+0], sv.x, a0); a0 = fmaf(w[0][4*q+1], sv.y, a0);
            a0 = fmaf(w[0][4*q+2], sv.z, a0); a0 = fmaf(w[0][4*q+3], sv.w, a0);
            a1 = fmaf(w[1][4*q+0], sv.x, a1); a1 = fmaf(w[1][4*q+1], sv.y, a1);
            a1 = fmaf(w[1][4*q+2], sv.z, a1); a1 = fmaf(w[1][4*q+3], sv.w, a1);
            a2 = fmaf(w[2][4*q+0], sv.x, a2); a2 = fmaf(w[2][4*q+1], sv.y, a2);
            a2 = fmaf(w[2][4*q+2], sv.z, a2); a2 = fmaf(w[2][4*q+3], sv.w, a2);
            a3 = fmaf(w[3][4*q+0], sv.x, a3); a3 = fmaf(w[3][4*q+1], sv.y, a3);
            a3 = fmaf(w[3][4*q+2], sv.z, a3); a3 = fmaf(w[3][4*q+3], sv.w, a3);
        }
        a0 = row16_allreduce(a0);
        a1 = row16_allreduce(a1);
        a2 = row16_allreduce(a2);
        a3 = row16_allreduce(a3);
        if (cgi == 0) {
            float4 p; p.x = a0; p.y = a1; p.z = a2; p.w = a3;
            *(float4*)&s_part[wave][4 * rg] = p;
        }
        __syncthreads();

        // ---- phase 3: finish 16 rows (threads 0..255), fold in W_in @ u_t, tanh, publish
        if (tid < 256) {
            const int row = tid >> 4;
            const int k   = tid & 15;
            float v = s_part[k][row];
#pragma unroll
            for (int e = 0; e < 4; ++e)
                v = fmaf(s_win[row][4 * k + e], s_u[4 * k + e], v);
            v = row16_allreduce(v);
            if (k == 0)
                out_states[(size_t)t * H + row0 + row] = tanhf(v);
        }
        grid.sync();
    }
}

__device__ __forceinline__ float wave64_allreduce(float x) {
#pragma unroll
    for (int m = 1; m < 64; m <<= 1) x += __shfl_xor(x, m, 64);
    return x;
}

// outputs[s][o] = W_out[o][0] + sum_i W_out[o][1+i]*u[s][i] + sum_h W_out[o][65+h]*x[s][h]
__global__ __launch_bounds__(512)
void esn_out(const float* __restrict__ inputs,
             const float* __restrict__ W_out,    // (OUTD, 1+IN+H) row-major
             const float* __restrict__ states,   // (SEQ, H)
             float* __restrict__ outputs)        // (SEQ, OUTD)
{
    const int s    = blockIdx.x * 8 + (threadIdx.x >> 6);
    const int lane = threadIdx.x & 63;
    const int K = 1 + IN + H; // 4161

    for (int o = 0; o < OUTD; ++o) {
        const float* wrow = W_out + (size_t)o * K;
        float acc = 0.f;
        for (int j = lane; j < K; j += 64) {
            float e;
            if (j == 0)       e = 1.0f;
            else if (j < 65)  e = inputs[(size_t)s * IN + (j - 1)];
            else              e = states[(size_t)s * H + (j - 65)];
            acc = fmaf(wrow[j], e, acc);
        }
        acc = wave64_allreduce(acc);
        if (lane == 0) outputs[(size_t)s * OUTD + o] = acc;
    }
}

extern "C" void kernel_launch(void* const* d_in, const int* in_sizes, int n_in,
                              void* d_out, int out_size, void* d_ws, size_t ws_size,
                              hipStream_t stream) {
    const float* inputs = (const float*)d_in[0];
    const float* W_in   = (const float*)d_in[1];
    const float* W_res  = (const float*)d_in[2];
    const float* W_out  = (const float*)d_in[3];

    float* outputs = (float*)d_out;                        // (SEQ, OUTD)
    float* states  = (float*)d_out + (size_t)SEQ * OUTD;   // (SEQ, H)
    float* zerobuf = (float*)d_ws;                         // H floats

    hipMemsetAsync(zerobuf, 0, H * sizeof(float), stream);

    void* args[] = { (void*)&inputs, (void*)&W_in, (void*)&W_res,
                     (void*)&states, (void*)&zerobuf };
    hipLaunchCooperativeKernel((void*)esn_scan, dim3(NBLK), dim3(NTHR),
                               args, 0, stream);

    esn_out<<<dim3(SEQ / 8), dim3(512), 0, stream>>>(inputs, W_out, states, outputs);
}

// Round 2
// 23466.920 us; speedup vs baseline: 5.0879x; 5.0879x over previous
//
#include <hip/hip_runtime.h>

#define H 4096
#define IN 64
#define OUTD 64
#define SEQ 4096
#define NBLK 256
#define ROWS_PER_BLK 16
#define NTHR 1024

// ---- device-coherent (L2-bypassing, L3-point) accessors -------------------
// sc0 sc1 = system-scope coherent on gfx950: loads read past the (non-cross-
// XCD-coherent) L2; stores are acknowledged at the L3 coherence point, so
// s_waitcnt vmcnt(0) == "globally visible". This lets the inter-block barrier
// run with NO cache-wide fences (the grid.sync killer in R1).

__device__ __forceinline__ float4 coherent_load_f4(const float4* p) {
    float4 v;
    asm volatile("global_load_dwordx4 %0, %1, off sc0 sc1\n\t"
                 "s_waitcnt vmcnt(0)"
                 : "=v"(v) : "v"(p) : "memory");
    return v;
}
__device__ __forceinline__ int coherent_load_i32(const int* p) {
    int v;
    asm volatile("global_load_dword %0, %1, off sc0 sc1\n\t"
                 "s_waitcnt vmcnt(0)"
                 : "=v"(v) : "v"(p) : "memory");
    return v;
}
__device__ __forceinline__ void coherent_store_f32(float* p, float v) {
    asm volatile("global_store_dword %0, %1, off sc0 sc1"
                 :: "v"(p), "v"(v) : "memory");
}
__device__ __forceinline__ void coherent_store_i32(int* p, int v) {
    asm volatile("global_store_dword %0, %1, off sc0 sc1"
                 :: "v"(p), "v"(v) : "memory");
}

__device__ __forceinline__ float row16_allreduce(float x) {
    // all-reduce across each 16-lane DPP row via rotate-and-add (VALU pipe)
    x += __int_as_float(__builtin_amdgcn_update_dpp(0, __float_as_int(x), 0x128, 0xf, 0xf, false)); // row_ror:8
    x += __int_as_float(__builtin_amdgcn_update_dpp(0, __float_as_int(x), 0x124, 0xf, 0xf, false)); // row_ror:4
    x += __int_as_float(__builtin_amdgcn_update_dpp(0, __float_as_int(x), 0x122, 0xf, 0xf, false)); // row_ror:2
    x += __int_as_float(__builtin_amdgcn_update_dpp(0, __float_as_int(x), 0x121, 0xf, 0xf, false)); // row_ror:1
    return x;
}

__global__ __launch_bounds__(NTHR, 4)
void esn_scan(const float* __restrict__ inputs,   // (SEQ, IN)
              const float* __restrict__ W_in,     // (H, IN)
              const float* __restrict__ W_res,    // (H, H)
              float* __restrict__ out_states,     // (SEQ, H) region of d_out
              int* __restrict__ flags)            // NBLK ints, zeroed at launch
{
    __shared__ alignas(16) float s_state[H];            // swizzled quads
    __shared__ alignas(16) float s_win[ROWS_PER_BLK][IN];
    __shared__ alignas(16) float s_part[16][16];        // [wave][row]
    __shared__ alignas(16) float s_u[IN];

    const int tid  = threadIdx.x;
    const int row0 = blockIdx.x * ROWS_PER_BLK;
    const int wave = tid >> 6;
    const int lane = tid & 63;
    const int rg   = lane >> 4;   // 0..3  (row group: rows 4*rg .. 4*rg+3)
    const int cgi  = lane & 15;   // 0..15 (col group: cols wave*256 + cgi*16 .. +16)

    // ---- stage W_in rows for this block (once)
    for (int idx = tid; idx < ROWS_PER_BLK * IN; idx += NTHR)
        (&s_win[0][0])[idx] = W_in[(size_t)row0 * IN + idx];

    // ---- load this lane's 64 fp32 weights into registers (once)
    float w[4][16];
    const int col0 = wave * 256 + cgi * 16;
#pragma unroll
    for (int j = 0; j < 4; ++j) {
        const float* src = W_res + (size_t)(row0 + 4 * rg + j) * H + col0;
#pragma unroll
        for (int q = 0; q < 4; ++q) {
            float4 v = *(const float4*)(src + 4 * q);
            w[j][4 * q + 0] = v.x; w[j][4 * q + 1] = v.y;
            w[j][4 * q + 2] = v.z; w[j][4 * q + 3] = v.w;
        }
    }

    float4* s_state4 = (float4*)s_state;

    for (int t = 0; t < SEQ; ++t) {
        // ---- phase 1: fused barrier-wait + state staging (global -> LDS, swizzled)
        // quad qi = tid; producer block of quad = qi>>2 (16 floats per block)
        {
            const int qi   = tid;
            const int w_   = qi >> 6;
            const int wi   = qi & 63;
            const int cg_  = wi >> 2;
            const int q_   = wi & 3;
            const int slot = w_ * 64 + q_ * 16 + cg_;
            if (t == 0) {
                s_state4[slot] = make_float4(0.f, 0.f, 0.f, 0.f);
            } else {
                const int prod = qi >> 2;
                // spin until producer published step t-1 (flags[prod] >= t).
                // flag at L3 => its state row-chunk is at L3 (publisher drained
                // vmcnt before setting flag). Append-only buffer => no WAR.
                while (coherent_load_i32(&flags[prod]) < t) { }
                float4 v = coherent_load_f4(
                    (const float4*)(out_states + (size_t)(t - 1) * H) + qi);
                s_state4[slot] = v;
            }
            if (tid < 16)
                ((float4*)s_u)[tid] = ((const float4*)(inputs + (size_t)t * IN))[tid];
        }
        __syncthreads();

        // ---- phase 2: 4 rows x 16 cols of FMA per lane, weights in VGPRs
        float a0 = 0.f, a1 = 0.f, a2 = 0.f, a3 = 0.f;
#pragma unroll
        for (int q = 0; q < 4; ++q) {
            float4 sv = s_state4[wave * 64 + q * 16 + cgi];
            a0 = fmaf(w[0][4*q+0], sv.x, a0); a0 = fmaf(w[0][4*q+1], sv.y, a0);
            a0 = fmaf(w[0][4*q+2], sv.z, a0); a0 = fmaf(w[0][4*q+3], sv.w, a0);
            a1 = fmaf(w[1][4*q+0], sv.x, a1); a1 = fmaf(w[1][4*q+1], sv.y, a1);
            a1 = fmaf(w[1][4*q+2], sv.z, a1); a1 = fmaf(w[1][4*q+3], sv.w, a1);
            a2 = fmaf(w[2][4*q+0], sv.x, a2); a2 = fmaf(w[2][4*q+1], sv.y, a2);
            a2 = fmaf(w[2][4*q+2], sv.z, a2); a2 = fmaf(w[2][4*q+3], sv.w, a2);
            a3 = fmaf(w[3][4*q+0], sv.x, a3); a3 = fmaf(w[3][4*q+1], sv.y, a3);
            a3 = fmaf(w[3][4*q+2], sv.z, a3); a3 = fmaf(w[3][4*q+3], sv.w, a3);
        }
        a0 = row16_allreduce(a0);
        a1 = row16_allreduce(a1);
        a2 = row16_allreduce(a2);
        a3 = row16_allreduce(a3);
        if (cgi == 0) {
            float4 p; p.x = a0; p.y = a1; p.z = a2; p.w = a3;
            *(float4*)&s_part[wave][4 * rg] = p;
        }
        __syncthreads();

        // ---- phase 3: finish 16 rows (threads 0..255), fold W_in @ u_t, tanh, publish
        if (tid < 256) {
            const int row = tid >> 4;
            const int k   = tid & 15;
            float v = s_part[k][row];
#pragma unroll
            for (int e = 0; e < 4; ++e)
                v = fmaf(s_win[row][4 * k + e], s_u[4 * k + e], v);
            v = row16_allreduce(v);
            if (k == 0)
                coherent_store_f32(&out_states[(size_t)t * H + row0 + row], tanhf(v));
        }
        // per-wave vmcnt drain, then block barrier: all row stores of this
        // block are at L3 once every wave passed the barrier.
        asm volatile("s_waitcnt vmcnt(0)" ::: "memory");
        __syncthreads();
        if (tid == 0)
            coherent_store_i32(&flags[blockIdx.x], t + 1);
    }
}

__device__ __forceinline__ float wave64_allreduce(float x) {
#pragma unroll
    for (int m = 1; m < 64; m <<= 1) x += __shfl_xor(x, m, 64);
    return x;
}

// outputs[s][o] = W_out[o][0] + sum_i W_out[o][1+i]*u[s][i] + sum_h W_out[o][65+h]*x[s][h]
__global__ __launch_bounds__(512)
void esn_out(const float* __restrict__ inputs,
             const float* __restrict__ W_out,    // (OUTD, 1+IN+H) row-major
             const float* __restrict__ states,   // (SEQ, H)
             float* __restrict__ outputs)        // (SEQ, OUTD)
{
    const int s    = blockIdx.x * 8 + (threadIdx.x >> 6);
    const int lane = threadIdx.x & 63;
    const int K = 1 + IN + H; // 4161

    for (int o = 0; o < OUTD; ++o) {
        const float* wrow = W_out + (size_t)o * K;
        float acc = 0.f;
        for (int j = lane; j < K; j += 64) {
            float e;
            if (j == 0)       e = 1.0f;
            else if (j < 65)  e = inputs[(size_t)s * IN + (j - 1)];
            else              e = states[(size_t)s * H + (j - 65)];
            acc = fmaf(wrow[j], e, acc);
        }
        acc = wave64_allreduce(acc);
        if (lane == 0) outputs[(size_t)s * OUTD + o] = acc;
    }
}

extern "C" void kernel_launch(void* const* d_in, const int* in_sizes, int n_in,
                              void* d_out, int out_size, void* d_ws, size_t ws_size,
                              hipStream_t stream) {
    const float* inputs = (const float*)d_in[0];
    const float* W_in   = (const float*)d_in[1];
    const float* W_res  = (const float*)d_in[2];
    const float* W_out  = (const float*)d_in[3];

    float* outputs = (float*)d_out;                        // (SEQ, OUTD)
    float* states  = (float*)d_out + (size_t)SEQ * OUTD;   // (SEQ, H)
    int*   flags   = (int*)d_ws;                           // NBLK ints

    hipMemsetAsync(flags, 0, NBLK * sizeof(int), stream);

    void* args[] = { (void*)&inputs, (void*)&W_in, (void*)&W_res,
                     (void*)&states, (void*)&flags };
    hipLaunchCooperativeKernel((void*)esn_scan, dim3(NBLK), dim3(NTHR),
                               args, 0, stream);

    esn_out<<<dim3(SEQ / 8), dim3(512), 0, stream>>>(inputs, W_out, states, outputs);
}

// Round 3
// 21946.579 us; speedup vs baseline: 5.4404x; 1.0693x over previous
//
#include <hip/hip_runtime.h>

#define H 4096
#define IN 64
#define OUTD 64
#define SEQ 4096
#define NBLK 256
#define ROWS_PER_BLK 16
#define NTHR 1024
#define SENT 0x7F7F7F7Fu   // 3.39e38f; tanh output in [-1,1] can never equal it

// ---- device-coherent (L2-bypassing, L3-point) accessors -------------------
__device__ __forceinline__ void cpoll4(const unsigned* p,
                                       uint4& a, uint4& b, uint4& c, uint4& d) {
    asm volatile(
        "global_load_dwordx4 %0, %4, off sc0 sc1\n\t"
        "global_load_dwordx4 %1, %4, off offset:16 sc0 sc1\n\t"
        "global_load_dwordx4 %2, %4, off offset:32 sc0 sc1\n\t"
        "global_load_dwordx4 %3, %4, off offset:48 sc0 sc1\n\t"
        "s_waitcnt vmcnt(0)"
        : "=&v"(a), "=&v"(b), "=&v"(c), "=&v"(d)
        : "v"(p) : "memory");
}
__device__ __forceinline__ void coherent_store_f32(float* p, float v) {
    asm volatile("global_store_dword %0, %1, off sc0 sc1"
                 :: "v"(p), "v"(v) : "memory");
}

__device__ __forceinline__ float row16_allreduce(float x) {
    // all-reduce across each 16-lane DPP row via rotate-and-add (VALU pipe)
    x += __int_as_float(__builtin_amdgcn_update_dpp(0, __float_as_int(x), 0x128, 0xf, 0xf, false)); // row_ror:8
    x += __int_as_float(__builtin_amdgcn_update_dpp(0, __float_as_int(x), 0x124, 0xf, 0xf, false)); // row_ror:4
    x += __int_as_float(__builtin_amdgcn_update_dpp(0, __float_as_int(x), 0x122, 0xf, 0xf, false)); // row_ror:2
    x += __int_as_float(__builtin_amdgcn_update_dpp(0, __float_as_int(x), 0x121, 0xf, 0xf, false)); // row_ror:1
    return x;
}

__global__ __launch_bounds__(NTHR, 4)
void esn_scan(const float* __restrict__ inputs,   // (SEQ, IN)
              const float* __restrict__ W_in,     // (H, IN)
              const float* __restrict__ W_res,    // (H, H)
              float* __restrict__ out_states)     // (SEQ, H), sentinel-prefilled
{
    __shared__ alignas(16) float s_win[ROWS_PER_BLK][65];   // padded (bank spread)
    __shared__ alignas(16) float s_part[2][16][20];         // [parity][wave][row(16)+pad]
    __shared__ alignas(16) float s_u[2][IN];                // [parity][64]

    const int tid  = threadIdx.x;
    const int row0 = blockIdx.x * ROWS_PER_BLK;
    const int wave = tid >> 6;
    const int lane = tid & 63;
    const int rg   = lane >> 4;   // 0..3  (rows 4*rg .. 4*rg+3 of this block)
    const int cgi  = lane & 15;   // 0..15 (cols wave*256 + cgi*16 .. +16)
    const int col0 = wave * 256 + cgi * 16;  // this lane's 16 state columns
    // those 16 columns are produced by exactly one block: col0/16 = wave*16+cgi

    // ---- stage W_in rows for this block (once)
    for (int idx = tid; idx < ROWS_PER_BLK * IN; idx += NTHR)
        s_win[idx >> 6][idx & 63] = W_in[(size_t)row0 * IN + idx];

    // ---- load this lane's 64 fp32 weights into registers (once)
    float w[4][16];
#pragma unroll
    for (int j = 0; j < 4; ++j) {
        const float* src = W_res + (size_t)(row0 + 4 * rg + j) * H + col0;
#pragma unroll
        for (int q = 0; q < 4; ++q) {
            float4 v = *(const float4*)(src + 4 * q);
            w[j][4 * q + 0] = v.x; w[j][4 * q + 1] = v.y;
            w[j][4 * q + 2] = v.z; w[j][4 * q + 3] = v.w;
        }
    }

    for (int t = 0; t < SEQ; ++t) {
        const int par = t & 1;
        if (tid < 16)
            ((float4*)s_u[par])[tid] = ((const float4*)(inputs + (size_t)t * IN))[tid];

        // ---- phase 1+2 fused: poll producer's 16 floats (sentinel = not yet
        // published), then 4x16 FMA entirely in registers.
        float a0 = 0.f, a1 = 0.f, a2 = 0.f, a3 = 0.f;
        if (t > 0) {
            const unsigned* p =
                (const unsigned*)(out_states + (size_t)(t - 1) * H + col0);
            uint4 q0, q1, q2, q3;
            for (;;) {
                cpoll4(p, q0, q1, q2, q3);
                const bool again =
                    (q0.x == SENT) | (q0.y == SENT) | (q0.z == SENT) | (q0.w == SENT) |
                    (q1.x == SENT) | (q1.y == SENT) | (q1.z == SENT) | (q1.w == SENT) |
                    (q2.x == SENT) | (q2.y == SENT) | (q2.z == SENT) | (q2.w == SENT) |
                    (q3.x == SENT) | (q3.y == SENT) | (q3.z == SENT) | (q3.w == SENT);
                if (!again) break;
            }
            float s[16];
            s[ 0] = __uint_as_float(q0.x); s[ 1] = __uint_as_float(q0.y);
            s[ 2] = __uint_as_float(q0.z); s[ 3] = __uint_as_float(q0.w);
            s[ 4] = __uint_as_float(q1.x); s[ 5] = __uint_as_float(q1.y);
            s[ 6] = __uint_as_float(q1.z); s[ 7] = __uint_as_float(q1.w);
            s[ 8] = __uint_as_float(q2.x); s[ 9] = __uint_as_float(q2.y);
            s[10] = __uint_as_float(q2.z); s[11] = __uint_as_float(q2.w);
            s[12] = __uint_as_float(q3.x); s[13] = __uint_as_float(q3.y);
            s[14] = __uint_as_float(q3.z); s[15] = __uint_as_float(q3.w);
#pragma unroll
            for (int e = 0; e < 16; ++e) {
                a0 = fmaf(w[0][e], s[e], a0);
                a1 = fmaf(w[1][e], s[e], a1);
                a2 = fmaf(w[2][e], s[e], a2);
                a3 = fmaf(w[3][e], s[e], a3);
            }
        }
        a0 = row16_allreduce(a0);
        a1 = row16_allreduce(a1);
        a2 = row16_allreduce(a2);
        a3 = row16_allreduce(a3);
        if (cgi == 0) {
            float4 pv; pv.x = a0; pv.y = a1; pv.z = a2; pv.w = a3;
            *(float4*)&s_part[par][wave][4 * rg] = pv;
        }
        __syncthreads();   // single barrier per step (parity double-buffering)

        // ---- phase 3: finish 16 rows (threads 0..255), fold W_in @ u_t, tanh, publish
        if (tid < 256) {
            const int row = tid >> 4;
            const int k   = tid & 15;
            float v = s_part[par][k][row];
#pragma unroll
            for (int e = 0; e < 4; ++e)
                v = fmaf(s_win[row][4 * k + e], s_u[par][4 * k + e], v);
            v = row16_allreduce(v);
            if (k == 0)
                coherent_store_f32(&out_states[(size_t)t * H + row0 + row], tanhf(v));
        }
        // no trailing barrier: next step writes parity^1 buffers; consumers of
        // our stores (other blocks AND our own lanes) gate on the sentinel.
    }
}

__device__ __forceinline__ float wave64_allreduce(float x) {
#pragma unroll
    for (int m = 1; m < 64; m <<= 1) x += __shfl_xor(x, m, 64);
    return x;
}

// outputs[s][o] = W_out[o][0] + sum_i W_out[o][1+i]*u[s][i] + sum_h W_out[o][65+h]*x[s][h]
__global__ __launch_bounds__(512)
void esn_out(const float* __restrict__ inputs,
             const float* __restrict__ W_out,    // (OUTD, 1+IN+H) row-major
             const float* __restrict__ states,   // (SEQ, H)
             float* __restrict__ outputs)        // (SEQ, OUTD)
{
    const int s    = blockIdx.x * 8 + (threadIdx.x >> 6);
    const int lane = threadIdx.x & 63;
    const int K = 1 + IN + H; // 4161

    for (int o = 0; o < OUTD; ++o) {
        const float* wrow = W_out + (size_t)o * K;
        float acc = 0.f;
        for (int j = lane; j < K; j += 64) {
            float e;
            if (j == 0)       e = 1.0f;
            else if (j < 65)  e = inputs[(size_t)s * IN + (j - 1)];
            else              e = states[(size_t)s * H + (j - 65)];
            acc = fmaf(wrow[j], e, acc);
        }
        acc = wave64_allreduce(acc);
        if (lane == 0) outputs[(size_t)s * OUTD + o] = acc;
    }
}

extern "C" void kernel_launch(void* const* d_in, const int* in_sizes, int n_in,
                              void* d_out, int out_size, void* d_ws, size_t ws_size,
                              hipStream_t stream) {
    const float* inputs = (const float*)d_in[0];
    const float* W_in   = (const float*)d_in[1];
    const float* W_res  = (const float*)d_in[2];
    const float* W_out  = (const float*)d_in[3];

    float* outputs = (float*)d_out;                        // (SEQ, OUTD)
    float* states  = (float*)d_out + (size_t)SEQ * OUTD;   // (SEQ, H)

    // Pre-fill states with sentinel: the inter-block handshake polls the data
    // itself (0x7F7F7F7F = 3.39e38, unreachable for tanh outputs).
    hipMemsetAsync(states, 0x7F, (size_t)SEQ * H * sizeof(float), stream);

    void* args[] = { (void*)&inputs, (void*)&W_in, (void*)&W_res, (void*)&states };
    hipLaunchCooperativeKernel((void*)esn_scan, dim3(NBLK), dim3(NTHR),
                               args, 0, stream);

    esn_out<<<dim3(SEQ / 8), dim3(512), 0, stream>>>(inputs, W_out, states, outputs);
}

// Round 4
// 10885.371 us; speedup vs baseline: 10.9686x; 2.0162x over previous
//
#include <hip/hip_runtime.h>

#define H 4096
#define IN 64
#define OUTD 64
#define SEQ 4096
#define NBLK 256
#define ROWS_PER_BLK 16
#define NTHR 1024
#define SENT 0x7F7F7F7Fu   // 3.39e38f; tanh output in [-1,1] can never equal it

// ---- device-coherent (L2-bypassing, L3-point) accessors -------------------
__device__ __forceinline__ uint4 cpoll1(const unsigned* p) {
    uint4 v;
    asm volatile("global_load_dwordx4 %0, %1, off sc0 sc1\n\t"
                 "s_waitcnt vmcnt(0)"
                 : "=&v"(v) : "v"(p) : "memory");
    return v;
}
__device__ __forceinline__ void coherent_store_f32(float* p, float v) {
    asm volatile("global_store_dword %0, %1, off sc0 sc1"
                 :: "v"(p), "v"(v) : "memory");
}

__device__ __forceinline__ float row16_allreduce(float x) {
    // all-reduce across each 16-lane DPP row via rotate-and-add (VALU pipe)
    x += __int_as_float(__builtin_amdgcn_update_dpp(0, __float_as_int(x), 0x128, 0xf, 0xf, false)); // row_ror:8
    x += __int_as_float(__builtin_amdgcn_update_dpp(0, __float_as_int(x), 0x124, 0xf, 0xf, false)); // row_ror:4
    x += __int_as_float(__builtin_amdgcn_update_dpp(0, __float_as_int(x), 0x122, 0xf, 0xf, false)); // row_ror:2
    x += __int_as_float(__builtin_amdgcn_update_dpp(0, __float_as_int(x), 0x121, 0xf, 0xf, false)); // row_ror:1
    return x;
}
__device__ __forceinline__ float quad4_allreduce(float x) {
    // all-reduce across 4-lane quads (quad_perm butterflies)
    x += __int_as_float(__builtin_amdgcn_update_dpp(0, __float_as_int(x), 0xB1, 0xf, 0xf, false)); // perm 1,0,3,2
    x += __int_as_float(__builtin_amdgcn_update_dpp(0, __float_as_int(x), 0x4E, 0xf, 0xf, false)); // perm 2,3,0,1
    return x;
}

__global__ __launch_bounds__(NTHR, 4)
void esn_scan(const float* __restrict__ inputs,   // (SEQ, IN)
              const float* __restrict__ W_in,     // (H, IN)
              const float* __restrict__ W_res,    // (H, H)
              float* __restrict__ out_states)     // (SEQ, H), sentinel-prefilled
{
    __shared__ alignas(16) float4 s_state4[H / 4];        // 1024 swizzled quads
    __shared__ alignas(16) float s_win[ROWS_PER_BLK][65]; // padded
    __shared__ alignas(16) float s_part[16][20];          // [k(wave)][row], padded
    __shared__ alignas(16) float s_u[IN];

    const int tid  = threadIdx.x;
    const int row0 = blockIdx.x * ROWS_PER_BLK;
    const int wave = tid >> 6;
    const int lane = tid & 63;
    const int rg   = lane >> 4;   // 0..3  (rows 4*rg .. 4*rg+3 of this block)
    const int cgi  = lane & 15;   // 0..15 (cols wave*256 + cgi*16 .. +16)
    const int col0 = wave * 256 + cgi * 16;

    // staging: thread polls ONE 16B quad: producer p = tid>>2, sub-quad q = tid&3
    // LDS slot = 64*(p>>4) + 16*q + (p&15)  (matches phase-2 read swizzle)
    const int sp    = tid >> 2;
    const int sq    = tid & 3;
    const int sslot = 64 * (sp >> 4) + 16 * sq + (sp & 15);
    const int scol  = sp * 16 + sq * 4;  // global state column of this quad

    // ---- stage W_in rows for this block (once)
    for (int idx = tid; idx < ROWS_PER_BLK * IN; idx += NTHR)
        s_win[idx >> 6][idx & 63] = W_in[(size_t)row0 * IN + idx];

    // ---- load this lane's 64 fp32 weights into registers (once)
    float w[4][16];
#pragma unroll
    for (int j = 0; j < 4; ++j) {
        const float* src = W_res + (size_t)(row0 + 4 * rg + j) * H + col0;
#pragma unroll
        for (int q = 0; q < 4; ++q) {
            float4 v = *(const float4*)(src + 4 * q);
            w[j][4 * q + 0] = v.x; w[j][4 * q + 1] = v.y;
            w[j][4 * q + 2] = v.z; w[j][4 * q + 3] = v.w;
        }
    }

    for (int t = 0; t < SEQ; ++t) {
        // ---- stage u_t (wave0 threads) and state row t-1 (all threads, 16B each)
        if (tid < 16)
            ((float4*)s_u)[tid] = ((const float4*)(inputs + (size_t)t * IN))[tid];
        if (t == 0) {
            s_state4[sslot] = make_float4(0.f, 0.f, 0.f, 0.f);
        } else {
            const unsigned* p =
                (const unsigned*)(out_states + (size_t)(t - 1) * H + scol);
            uint4 v;
            for (;;) {
                v = cpoll1(p);
                if ((v.x != SENT) & (v.y != SENT) & (v.z != SENT) & (v.w != SENT))
                    break;
                __builtin_amdgcn_s_sleep(1);   // gentle backoff: cut fabric spam
            }
            float4 f;
            f.x = __uint_as_float(v.x); f.y = __uint_as_float(v.y);
            f.z = __uint_as_float(v.z); f.w = __uint_as_float(v.w);
            s_state4[sslot] = f;
        }
        __syncthreads();   // B1: state staged

        // ---- phase 2: 4 rows x 16 cols of FMA per lane, weights in regs
        float a0 = 0.f, a1 = 0.f, a2 = 0.f, a3 = 0.f;
#pragma unroll
        for (int q = 0; q < 4; ++q) {
            float4 sv = s_state4[wave * 64 + q * 16 + cgi];
            a0 = fmaf(w[0][4*q+0], sv.x, a0); a0 = fmaf(w[0][4*q+1], sv.y, a0);
            a0 = fmaf(w[0][4*q+2], sv.z, a0); a0 = fmaf(w[0][4*q+3], sv.w, a0);
            a1 = fmaf(w[1][4*q+0], sv.x, a1); a1 = fmaf(w[1][4*q+1], sv.y, a1);
            a1 = fmaf(w[1][4*q+2], sv.z, a1); a1 = fmaf(w[1][4*q+3], sv.w, a1);
            a2 = fmaf(w[2][4*q+0], sv.x, a2); a2 = fmaf(w[2][4*q+1], sv.y, a2);
            a2 = fmaf(w[2][4*q+2], sv.z, a2); a2 = fmaf(w[2][4*q+3], sv.w, a2);
            a3 = fmaf(w[3][4*q+0], sv.x, a3); a3 = fmaf(w[3][4*q+1], sv.y, a3);
            a3 = fmaf(w[3][4*q+2], sv.z, a3); a3 = fmaf(w[3][4*q+3], sv.w, a3);
        }
        a0 = row16_allreduce(a0);
        a1 = row16_allreduce(a1);
        a2 = row16_allreduce(a2);
        a3 = row16_allreduce(a3);
        if (cgi == 0) {
            float4 pv; pv.x = a0; pv.y = a1; pv.z = a2; pv.w = a3;
            *(float4*)&s_part[wave][4 * rg] = pv;   // 80B row stride: 16B-aligned
        }
        __syncthreads();   // B2: partials visible

        // ---- phase 3: wave0 alone finishes all 16 rows; one 64B store.
        // waves 1..15 fall through to next step's polls (overlap with finish).
        if (wave == 0) {
            const int row = lane >> 2;  // 0..15
            const int j   = lane & 3;   // partial group
            float v = s_part[4*j+0][row] + s_part[4*j+1][row]
                    + s_part[4*j+2][row] + s_part[4*j+3][row];
#pragma unroll
            for (int e = 0; e < 16; ++e)
                v = fmaf(s_win[row][16*j + e], s_u[16*j + e], v);
            v = quad4_allreduce(v);
            if (j == 0)
                coherent_store_f32(&out_states[(size_t)t * H + row0 + row], tanhf(v));
        }
        // no trailing barrier: consumers (incl. our own next-step polls) gate on
        // the sentinel; s_part/s_win/s_u reuse is protected by B1/B2 ordering.
    }
}

__device__ __forceinline__ float wave64_allreduce(float x) {
#pragma unroll
    for (int m = 1; m < 64; m <<= 1) x += __shfl_xor(x, m, 64);
    return x;
}

// outputs[s][o] = W_out[o][0] + sum_i W_out[o][1+i]*u[s][i] + sum_h W_out[o][65+h]*x[s][h]
__global__ __launch_bounds__(512)
void esn_out(const float* __restrict__ inputs,
             const float* __restrict__ W_out,    // (OUTD, 1+IN+H) row-major
             const float* __restrict__ states,   // (SEQ, H)
             float* __restrict__ outputs)        // (SEQ, OUTD)
{
    const int s    = blockIdx.x * 8 + (threadIdx.x >> 6);
    const int lane = threadIdx.x & 63;
    const int K = 1 + IN + H; // 4161

    for (int o = 0; o < OUTD; ++o) {
        const float* wrow = W_out + (size_t)o * K;
        float acc = 0.f;
        for (int j = lane; j < K; j += 64) {
            float e;
            if (j == 0)       e = 1.0f;
            else if (j < 65)  e = inputs[(size_t)s * IN + (j - 1)];
            else              e = states[(size_t)s * H + (j - 65)];
            acc = fmaf(wrow[j], e, acc);
        }
        acc = wave64_allreduce(acc);
        if (lane == 0) outputs[(size_t)s * OUTD + o] = acc;
    }
}

extern "C" void kernel_launch(void* const* d_in, const int* in_sizes, int n_in,
                              void* d_out, int out_size, void* d_ws, size_t ws_size,
                              hipStream_t stream) {
    const float* inputs = (const float*)d_in[0];
    const float* W_in   = (const float*)d_in[1];
    const float* W_res  = (const float*)d_in[2];
    const float* W_out  = (const float*)d_in[3];

    float* outputs = (float*)d_out;                        // (SEQ, OUTD)
    float* states  = (float*)d_out + (size_t)SEQ * OUTD;   // (SEQ, H)

    // Pre-fill states with sentinel: the inter-block handshake polls the data
    // itself (0x7F7F7F7F = 3.39e38, unreachable for tanh outputs).
    hipMemsetAsync(states, 0x7F, (size_t)SEQ * H * sizeof(float), stream);

    void* args[] = { (void*)&inputs, (void*)&W_in, (void*)&W_res, (void*)&states };
    hipLaunchCooperativeKernel((void*)esn_scan, dim3(NBLK), dim3(NTHR),
                               args, 0, stream);

    esn_out<<<dim3(SEQ / 8), dim3(512), 0, stream>>>(inputs, W_out, states, outputs);
}